// Round 2
// baseline (139.982 us; speedup 1.0000x reference)
//
#include <hip/hip_runtime.h>

#define GH 32
#define GW 32
#define P  33              // LDS pitch: conflict-free for BOTH row and column access
#define INFV 1000000000.0f
#define EPSV 1e-6f

// One wave (64 lanes) per batch; lanes 0..31 active (lane = row in row-mode,
// lane = column in col-mode), lanes 32..63 hold INF and self-neutralize
// (their fl(INF+x) >= INF never wins a strict '<'), providing the grid
// boundary for the wrapping lane +-1 shuffles for free.
//
// Directional wavefront passes (parallel fast-sweeping): per pass, serial
// over the 32 cross-wavefront positions; each step relaxes one full grid
// line in parallel with ALL 8 neighbors — the already-swept side via
// shuffles of just-updated values (Gauss-Seidel), the ahead side via old
// values — plus one vertical mini-relax to absorb length-1 jogs.
// Pass cycle: R (row,fwd), D (col,fwd), L (row,bwd), U (col,bwd); the
// orientation switch is just LDS addressing (pitch 33 is conflict-free
// both ways), so no transpose step exists.
//
// Exactness: every update is d = min(d, fl(w + d_neighbor)) — identical
// relaxation ops to the reference, different order. All finite values are
// float-evaluated walk sums from the source; exit happens only after a
// complete pass with no change, i.e. every cell verified all 8 neighbor
// inequalities at final values => unique least fixed point => dist is
// bit-identical to the reference's 1024 Jacobi sweeps => same backtrack.

// STEP(J, VB): relax cell at index J of the lane's line. Carried state:
//   cu,cd = shfl up/dn of the just-updated previous cell (current diagonals)
//   ca    = previous cell value in-lane (current)
//   u0c,d0c = shfl up/dn of v[J] (old, carried from last step's u1/d1)
// VB = ahead-side in-lane value (old).
#define STEP(J, VB) {                                                      \
    const float vj = v[J];                                                 \
    const float u1 = __shfl(VB, tid - 1), d1 = __shfl(VB, tid + 1);        \
    const float nmin = fminf(fminf(fminf(cu, cd), fminf(u0c, d0c)),        \
                             fminf(fminf(u1, d1), fminf(ca, VB)));         \
    const float nd = wv[J] + nmin;                                         \
    float vn = vj;                                                         \
    if (nd < vn) { vn = nd; ch = true; }                                   \
    const float mu = __shfl(vn, tid - 1), md = __shfl(vn, tid + 1);        \
    const float nd2 = wv[J] + fminf(mu, md);    /* vertical mini-relax */  \
    if (nd2 < vn) { vn = nd2; ch = true; }                                 \
    v[J] = vn;                                                             \
    cu = mu; cd = md; ca = vn; u0c = u1; d0c = d1;                         \
}

__global__ __launch_bounds__(64)
void bbastar_kernel(const float* __restrict__ weights,
                    const int* __restrict__ source,
                    const int* __restrict__ target,
                    float* __restrict__ out) {
    __shared__ float d[GH * P];
    __shared__ float wl[GH * P];   // w + EPS, pitch-33

    const int b   = blockIdx.x;
    const int tid = threadIdx.x;   // 0..63, single wave
    const int sr = source[2 * b];
    const int sc = source[2 * b + 1];

    // zero this batch's output region (harness poisons d_out with 0xAA)
    float4* ob4 = (float4*)(out + b * (GH * GW));
    #pragma unroll
    for (int k = 0; k < 4; ++k) ob4[tid + 64 * k] = make_float4(0.f, 0.f, 0.f, 0.f);

    // stage w (+EPS) into LDS, coalesced float4 global reads
    const float* wb = weights + b * (GH * GW);
    #pragma unroll
    for (int k = 0; k < 4; ++k) {
        const int idx = tid + 64 * k;            // float4 index, 256 total
        const float4 v4 = ((const float4*)wb)[idx];
        const int e = idx * 4;
        const int r = e >> 5, c = e & 31;
        wl[r * P + c    ] = v4.x + EPSV;
        wl[r * P + c + 1] = v4.y + EPSV;
        wl[r * P + c + 2] = v4.z + EPSV;
        wl[r * P + c + 3] = v4.w + EPSV;
    }
    for (int i = tid; i < GH * P; i += 64) d[i] = INFV;
    __syncthreads();
    if (tid == 0) d[sr * P + sc] = wl[sr * P + sc];   // source = w[source]+EPS
    __syncthreads();

    for (int pass = 0; pass < 256; ++pass) {
        const int  mode = pass & 3;        // 0:R 1:D 2:L 3:U
        const bool colm = mode & 1;
        float v[32], wv[32];
        if (tid < 32) {
            #pragma unroll
            for (int j = 0; j < 32; ++j) {
                const int a = colm ? (j * P + tid) : (tid * P + j);
                v[j]  = d[a];
                wv[j] = wl[a];
            }
        } else {
            #pragma unroll
            for (int j = 0; j < 32; ++j) { v[j] = INFV; wv[j] = INFV; }
        }

        bool ch = false;
        float cu = INFV, cd = INFV, ca = INFV, u0c, d0c;
        if (!(mode & 2)) {                 // forward: j = 0..31
            u0c = __shfl(v[0], tid - 1); d0c = __shfl(v[0], tid + 1);
            #pragma unroll
            for (int s = 0; s < 32; ++s) {
                const float vb = (s < 31) ? v[s + 1] : INFV;
                STEP(s, vb)
            }
        } else {                           // backward: j = 31..0
            u0c = __shfl(v[31], tid - 1); d0c = __shfl(v[31], tid + 1);
            #pragma unroll
            for (int s = 0; s < 32; ++s) {
                const int j = 31 - s;
                const float vb = (j > 0) ? v[j - 1] : INFV;
                STEP(j, vb)
            }
        }

        if (tid < 32) {
            #pragma unroll
            for (int j = 0; j < 32; ++j)
                d[colm ? (j * P + tid) : (tid * P + j)] = v[j];
        }
        __syncthreads();                   // single wave: cheap; orders LDS
        if (__ballot(ch) == 0ULL) break;   // certified fixed point
    }

    // Greedy backtrack, lane 0 only. Bounds-checked reads replicate the
    // reference's where(valid, dvals, INF); strict '<' scan in OFFS order
    // replicates jnp.argmin first-min tie-breaking.
    if (tid == 0) {
        const int drr[8] = {-1, -1, -1,  0, 0,  1, 1, 1};
        const int dcc[8] = {-1,  0,  1, -1, 1, -1, 0, 1};
        int pr = target[2 * b];
        int pc = target[2 * b + 1];
        float* ob = out + b * (GH * GW);
        for (int step = 0; step < GH * GW; ++step) {
            ob[pr * GW + pc] = 1.0f;
            if (pr == sr && pc == sc) break;
            float best = INFV;
            int bj = 0;
            #pragma unroll
            for (int j = 0; j < 8; ++j) {
                const int nr = pr + drr[j], nc = pc + dcc[j];
                const bool ok = (nr >= 0) & (nr < GH) & (nc >= 0) & (nc < GW);
                const int cr = min(max(nr, 0), GH - 1);
                const int cc = min(max(nc, 0), GW - 1);
                const float vv = ok ? d[cr * P + cc] : INFV;
                if (vv < best) { best = vv; bj = j; }
            }
            pr += drr[bj];
            pc += dcc[bj];
        }
    }
}

extern "C" void kernel_launch(void* const* d_in, const int* in_sizes, int n_in,
                              void* d_out, int out_size, void* d_ws, size_t ws_size,
                              hipStream_t stream) {
    const float* weights = (const float*)d_in[0];
    const int*   source  = (const int*)d_in[1];
    const int*   target  = (const int*)d_in[2];
    float*       out     = (float*)d_out;
    const int B = in_sizes[0] / (GH * GW);
    bbastar_kernel<<<B, 64, 0, stream>>>(weights, source, target, out);
}

// Round 4
// 91.815 us; speedup vs baseline: 1.5246x; 1.5246x over previous
//
#include <hip/hip_runtime.h>

#define GH 32
#define GW 32
#define P  33              // LDS pitch for the final publish (backtrack only)
#define INFV 1000000000.0f
#define EPSV 1e-6f

// One wave (64 lanes) per batch. Lane owns a 4x4 register tile:
// tr = tid>>3 (tile row 0..7), tc = tid&7 (tile col 0..7).
// Per sweep: ring exchange of tile borders via 20 __shfl (neighbor tiles are
// neighbor lanes — no LDS, no barrier), then forward+backward in-tile
// Gauss-Seidel with all 8 neighbors. Cross-tile is Jacobi (pre-sweep values).
// ALL shuffles execute unconditionally under full exec (ds_bpermute is
// push-based: inactive source lanes supply no data), with the boundary
// INFV selected AFTER the shuffle.
//
// Exactness: every update is d = min(d, fl(w + d_n)) — the same monotone
// relaxation the reference's Jacobi sweeps perform, in a different order;
// all finite values are float-evaluated walk sums from the source. One of
// our sweeps refines a Jacobi step, so <=1024 sweeps reach the reference's
// fixed point; fl(v+w) >= v makes longer walks never smaller, so the
// reference's 1024 Jacobi sweeps are themselves converged.
//
// Certified early termination (Dijkstra threshold): terminate when every
// value written this sweep is STRICTLY greater than d[target]. Induction
// (improvement at y must use a neighbor value written after y last read
// that neighbor; ring snapshots + per-sweep chmin cover all such writes):
// every future write is fl(w + v_n) >= v_n > dtgt. Hence (a) target never
// improves again, and (b) any cell whose final value is <= dtgt already
// holds its final value (a future write of its final value would be
// <= dtgt — impossible). The backtrack's winner chain has values
// <= dtgt (min-neighbor <= cell value), so every winner is final; inflated
// non-winner values only lose in the first-strict-min scan (for j < j*,
// v_j >= final_j > final_j* = v_j*; for j > j*, v_j >= v_j* never wins
// strict '<'). The path is therefore identical to the reference's.

#define RELAX(i,j) {                                                          \
    const float ul = ((i)==0) ? top[(j)]   : (((j)==0) ? lft[(i)-1] : t[(i)-1][(j)-1]); \
    const float uu = ((i)==0) ? top[(j)+1] : t[(i)-1][(j)];                    \
    const float ur = ((i)==0) ? top[(j)+2] : (((j)==3) ? rgt[(i)-1] : t[(i)-1][(j)+1]); \
    const float ll = ((j)==0) ? lft[(i)]   : t[(i)][(j)-1];                    \
    const float rr = ((j)==3) ? rgt[(i)]   : t[(i)][(j)+1];                    \
    const float dl = ((i)==3) ? bot[(j)]   : (((j)==0) ? lft[(i)+1] : t[(i)+1][(j)-1]); \
    const float dd = ((i)==3) ? bot[(j)+1] : t[(i)+1][(j)];                    \
    const float dr = ((i)==3) ? bot[(j)+2] : (((j)==3) ? rgt[(i)+1] : t[(i)+1][(j)+1]); \
    const float nmin = fminf(fminf(fminf(ul, uu), fminf(ur, ll)),             \
                             fminf(fminf(rr, dl), fminf(dd, dr)));            \
    const float nd = w[i][j] + nmin;                                          \
    if (nd < t[i][j]) { t[i][j] = nd; ch = true; chmin = fminf(chmin, nd); }  \
}

__global__ __launch_bounds__(64)
void bbastar_kernel(const float* __restrict__ weights,
                    const int* __restrict__ source,
                    const int* __restrict__ target,
                    float* __restrict__ out) {
    __shared__ float d[GH * P];

    const int b   = blockIdx.x;
    const int tid = threadIdx.x;       // 0..63, single wave
    const int tr  = tid >> 3;          // tile row 0..7
    const int tc  = tid & 7;           // tile col 0..7
    const int r0  = tr << 2;
    const int c0  = tc << 2;

    const int sr  = source[2 * b];
    const int sc  = source[2 * b + 1];
    const int tgr = target[2 * b];
    const int tgc = target[2 * b + 1];

    // weight tile -> registers (float4, 16B aligned), +EPS (matches reference)
    float w[4][4], t[4][4];
    const float* wb = weights + b * (GH * GW);
    #pragma unroll
    for (int i = 0; i < 4; ++i) {
        const float4 v = *(const float4*)(wb + (r0 + i) * GW + c0);
        w[i][0] = v.x + EPSV; w[i][1] = v.y + EPSV;
        w[i][2] = v.z + EPSV; w[i][3] = v.w + EPSV;
    }

    // zero this batch's output region (harness poisons d_out with 0xAA)
    float4* ob4 = (float4*)(out + b * (GH * GW));
    #pragma unroll
    for (int k = 0; k < 4; ++k) ob4[tid + 64 * k] = make_float4(0.f, 0.f, 0.f, 0.f);

    // dist tile: INF, then source = w[source] (static register indexing only)
    #pragma unroll
    for (int i = 0; i < 4; ++i)
        #pragma unroll
        for (int j = 0; j < 4; ++j) t[i][j] = INFV;
    #pragma unroll
    for (int i = 0; i < 4; ++i)
        #pragma unroll
        for (int j = 0; j < 4; ++j)
            if (sr == r0 + i && sc == c0 + j) t[i][j] = w[i][j];

    // target owner lane + in-tile index (wave-uniform scalars)
    const int  tl = ((tgr >> 2) << 3) | (tgc >> 2);
    const int  ti = tgr & 3;
    const int  tj = tgc & 3;
    const bool hu = tr > 0, hd = tr < 7, hl = tc > 0, hr = tc < 7;

    for (int sweep = 0; sweep < 8192; ++sweep) {
        // ring exchange: unconditional full-exec shuffles, THEN boundary select
        float top[6], bot[6], lft[4], rgt[4];
        #pragma unroll
        for (int j = 0; j < 4; ++j) {
            const float su = __shfl(t[3][j], (tid - 8) & 63);
            const float sd = __shfl(t[0][j], (tid + 8) & 63);
            top[j + 1] = hu ? su : INFV;
            bot[j + 1] = hd ? sd : INFV;
        }
        {
            const float s_tl = __shfl(t[3][3], (tid - 9) & 63);
            const float s_tr = __shfl(t[3][0], (tid - 7) & 63);
            const float s_bl = __shfl(t[0][3], (tid + 7) & 63);
            const float s_br = __shfl(t[0][0], (tid + 9) & 63);
            top[0] = (hu && hl) ? s_tl : INFV;
            top[5] = (hu && hr) ? s_tr : INFV;
            bot[0] = (hd && hl) ? s_bl : INFV;
            bot[5] = (hd && hr) ? s_br : INFV;
        }
        #pragma unroll
        for (int i = 0; i < 4; ++i) {
            const float sl = __shfl(t[i][3], (tid - 1) & 63);
            const float sr2 = __shfl(t[i][0], (tid + 1) & 63);
            lft[i] = hl ? sl : INFV;
            rgt[i] = hr ? sr2 : INFV;
        }

        bool ch = false;
        float chmin = INFV;
        // forward in-tile Gauss-Seidel
        #pragma unroll
        for (int i = 0; i < 4; ++i)
            #pragma unroll
            for (int j = 0; j < 4; ++j) RELAX(i, j)
        // backward in-tile Gauss-Seidel
        #pragma unroll
        for (int i = 3; i >= 0; --i)
            #pragma unroll
            for (int j = 3; j >= 0; --j) RELAX(i, j)

        // current d[target]: owner lane selects (static indexing), broadcast
        float tv = t[0][0];
        #pragma unroll
        for (int i = 0; i < 4; ++i)
            #pragma unroll
            for (int j = 0; j < 4; ++j)
                if (ti == i && tj == j) tv = t[i][j];
        const float dtgt = __shfl(tv, tl);

        // continue while any change is <= d[target]; terminate only when all
        // changes are strictly above it (closes the float-tie hole)
        const bool pred = ch && (chmin <= dtgt);
        if (__ballot(pred) == 0ULL) break;
    }

    // publish final tiles for the backtrack
    #pragma unroll
    for (int i = 0; i < 4; ++i)
        #pragma unroll
        for (int j = 0; j < 4; ++j)
            d[(r0 + i) * P + (c0 + j)] = t[i][j];
    __syncthreads();

    // Greedy backtrack, lane 0 only. Bounds-checked reads replicate the
    // reference's where(valid, dvals, INF); strict '<' scan in OFFS order
    // replicates jnp.argmin first-min tie-breaking.
    if (tid == 0) {
        const int drr[8] = {-1, -1, -1,  0, 0,  1, 1, 1};
        const int dcc[8] = {-1,  0,  1, -1, 1, -1, 0, 1};
        int pr = tgr;
        int pc = tgc;
        float* ob = out + b * (GH * GW);
        for (int step = 0; step < GH * GW; ++step) {
            ob[pr * GW + pc] = 1.0f;
            if (pr == sr && pc == sc) break;
            float best = INFV;
            int bj = 0;
            #pragma unroll
            for (int j = 0; j < 8; ++j) {
                const int nr = pr + drr[j], nc = pc + dcc[j];
                const bool ok = (nr >= 0) & (nr < GH) & (nc >= 0) & (nc < GW);
                const int cr = min(max(nr, 0), GH - 1);
                const int cc = min(max(nc, 0), GW - 1);
                const float vv = ok ? d[cr * P + cc] : INFV;
                if (vv < best) { best = vv; bj = j; }
            }
            pr += drr[bj];
            pc += dcc[bj];
        }
    }
}

extern "C" void kernel_launch(void* const* d_in, const int* in_sizes, int n_in,
                              void* d_out, int out_size, void* d_ws, size_t ws_size,
                              hipStream_t stream) {
    const float* weights = (const float*)d_in[0];
    const int*   source  = (const int*)d_in[1];
    const int*   target  = (const int*)d_in[2];
    float*       out     = (float*)d_out;
    const int B = in_sizes[0] / (GH * GW);
    bbastar_kernel<<<B, 64, 0, stream>>>(weights, source, target, out);
}

// Round 5
// 76.351 us; speedup vs baseline: 1.8334x; 1.2025x over previous
//
#include <hip/hip_runtime.h>

#define GH 32
#define GW 32
#define P  34              // 32 + 2 halo; halo stays INF forever (OOB + ring + backtrack)
#define NP (P * P)
#define INFV 1000000000.0f
#define EPSV 1e-6f

// One wave (64 lanes) per batch. Lane owns a 4x4 register tile:
// tr = tid>>3, tc = tid&7; global tile origin (r0,c0) = (tr*4, tc*4).
// LDS d[34][34] holds the dist field with a permanent-INF halo, so ring
// reads and the backtrack need no boundary selects/clamps at all.
//
// Loop unit = { ring-read (20 LDS) ; one 16-cell in-tile Gauss-Seidel pass ;
// border-write (12 LDS) ; barrier }. Units alternate fwd/bwd in-tile order.
// Each unit advances cross-tile (Jacobi) propagation by one tile boundary —
// exchange-per-pass doubles crossings/cycle vs exchange-per-(fwd+bwd)-sweep.
// Change detection + ballot only on bwd units: a bwd pass with no change is
// a full all-8-neighbor verification of the current field => fixed point,
// regardless of what the preceding fwd pass changed.
//
// Exactness: every update is t = min(t, fl(w + v_n)) where v_n is a genuine
// float walk-sum from the source (registers or ring snapshot). Monotone
// decrease over the same value set as the reference's Jacobi iteration;
// termination only at the verified no-improvement point = unique least
// fixed point = the reference's converged dist (weights > 0 => optimal
// walks are simple, <= 1023 hops <= its 1024 sweeps). Backtrack uses the
// same first-strict-min scan in OFFS order => identical path/tie-breaking.

#define NMIN8(ul,uu,ur,ll,rr,dl,dd,dr) \
    fminf(fminf(fminf(fminf((ul),(uu)),(ur)), fminf(fminf((ll),(rr)),(dl))), fminf((dd),(dr)))

#define RELAXF(i,j) {                                                         \
    const float ul = ((i)==0) ? top[(j)]   : (((j)==0) ? lft[(i)-1] : t[(i)-1][(j)-1]); \
    const float uu = ((i)==0) ? top[(j)+1] : t[(i)-1][(j)];                    \
    const float ur = ((i)==0) ? top[(j)+2] : (((j)==3) ? rgt[(i)-1] : t[(i)-1][(j)+1]); \
    const float ll = ((j)==0) ? lft[(i)]   : t[(i)][(j)-1];                    \
    const float rr = ((j)==3) ? rgt[(i)]   : t[(i)][(j)+1];                    \
    const float dl = ((i)==3) ? bot[(j)]   : (((j)==0) ? lft[(i)+1] : t[(i)+1][(j)-1]); \
    const float dd = ((i)==3) ? bot[(j)+1] : t[(i)+1][(j)];                    \
    const float dr = ((i)==3) ? bot[(j)+2] : (((j)==3) ? rgt[(i)+1] : t[(i)+1][(j)+1]); \
    const float nd = w[i][j] + NMIN8(ul,uu,ur,ll,rr,dl,dd,dr);                \
    t[i][j] = fminf(t[i][j], nd);                                             \
}

#define RELAXB(i,j) {                                                         \
    const float ul = ((i)==0) ? top[(j)]   : (((j)==0) ? lft[(i)-1] : t[(i)-1][(j)-1]); \
    const float uu = ((i)==0) ? top[(j)+1] : t[(i)-1][(j)];                    \
    const float ur = ((i)==0) ? top[(j)+2] : (((j)==3) ? rgt[(i)-1] : t[(i)-1][(j)+1]); \
    const float ll = ((j)==0) ? lft[(i)]   : t[(i)][(j)-1];                    \
    const float rr = ((j)==3) ? rgt[(i)]   : t[(i)][(j)+1];                    \
    const float dl = ((i)==3) ? bot[(j)]   : (((j)==0) ? lft[(i)+1] : t[(i)+1][(j)-1]); \
    const float dd = ((i)==3) ? bot[(j)+1] : t[(i)+1][(j)];                    \
    const float dr = ((i)==3) ? bot[(j)+2] : (((j)==3) ? rgt[(i)+1] : t[(i)+1][(j)+1]); \
    const float nd = w[i][j] + NMIN8(ul,uu,ur,ll,rr,dl,dd,dr);                \
    ch = ch || (nd < t[i][j]);                                                \
    t[i][j] = fminf(t[i][j], nd);                                             \
}

#define RINGREAD {                                                            \
    _Pragma("unroll")                                                         \
    for (int k = 0; k < 6; ++k) {                                             \
        top[k] = d[base - P - 1 + k];                                         \
        bot[k] = d[base + 4 * P - 1 + k];                                     \
    }                                                                         \
    _Pragma("unroll")                                                         \
    for (int i = 0; i < 4; ++i) {                                             \
        lft[i] = d[base + i * P - 1];                                         \
        rgt[i] = d[base + i * P + 4];                                         \
    }                                                                         \
}

#define BORDERWRITE {                                                         \
    _Pragma("unroll")                                                         \
    for (int j = 0; j < 4; ++j) {                                             \
        d[base + j]         = t[0][j];                                        \
        d[base + 3 * P + j] = t[3][j];                                        \
    }                                                                         \
    d[base + P]         = t[1][0];                                            \
    d[base + 2 * P]     = t[2][0];                                            \
    d[base + P + 3]     = t[1][3];                                            \
    d[base + 2 * P + 3] = t[2][3];                                            \
}

__global__ __launch_bounds__(64)
void bbastar_kernel(const float* __restrict__ weights,
                    const int* __restrict__ source,
                    const int* __restrict__ target,
                    float* __restrict__ out) {
    __shared__ float d[NP];

    const int b   = blockIdx.x;
    const int tid = threadIdx.x;       // 0..63, single wave
    const int tr  = tid >> 3;
    const int tc  = tid & 7;
    const int r0  = tr << 2;
    const int c0  = tc << 2;
    const int base = (r0 + 1) * P + (c0 + 1);   // LDS addr of cell (r0,c0)

    const int sr  = source[2 * b];
    const int sc  = source[2 * b + 1];

    // weight tile -> registers (float4, aligned), +EPS (matches reference)
    float w[4][4], t[4][4];
    const float* wb = weights + b * (GH * GW);
    #pragma unroll
    for (int i = 0; i < 4; ++i) {
        const float4 v = *(const float4*)(wb + (r0 + i) * GW + c0);
        w[i][0] = v.x + EPSV; w[i][1] = v.y + EPSV;
        w[i][2] = v.z + EPSV; w[i][3] = v.w + EPSV;
    }

    // zero this batch's output region (harness poisons d_out with 0xAA)
    float4* ob4 = (float4*)(out + b * (GH * GW));
    #pragma unroll
    for (int k = 0; k < 4; ++k) ob4[tid + 64 * k] = make_float4(0.f, 0.f, 0.f, 0.f);

    // dist: INF everywhere (incl. permanent halo)
    for (int i = tid; i < NP; i += 64) d[i] = INFV;
    #pragma unroll
    for (int i = 0; i < 4; ++i)
        #pragma unroll
        for (int j = 0; j < 4; ++j) t[i][j] = INFV;
    __syncthreads();

    // source = w[source] (owner lane, static register indexing + one LDS write)
    #pragma unroll
    for (int i = 0; i < 4; ++i)
        #pragma unroll
        for (int j = 0; j < 4; ++j)
            if (sr == r0 + i && sc == c0 + j) {
                t[i][j] = w[i][j];
                d[base + i * P + j] = w[i][j];
            }
    __syncthreads();

    float top[6], bot[6], lft[4], rgt[4];
    for (int pair = 0; pair < 2048; ++pair) {
        // ---- fwd unit (no change tracking) ----
        RINGREAD
        #pragma unroll
        for (int i = 0; i < 4; ++i)
            #pragma unroll
            for (int j = 0; j < 4; ++j) RELAXF(i, j)
        BORDERWRITE
        __syncthreads();

        // ---- bwd unit (tracks changes; certifies on exit) ----
        RINGREAD
        bool ch = false;
        #pragma unroll
        for (int i = 3; i >= 0; --i)
            #pragma unroll
            for (int j = 3; j >= 0; --j) RELAXB(i, j)
        BORDERWRITE
        __syncthreads();
        if (__ballot(ch) == 0ULL) break;   // verified all-8-neighbor fixed point
    }

    // publish full tiles for the backtrack
    #pragma unroll
    for (int i = 0; i < 4; ++i)
        #pragma unroll
        for (int j = 0; j < 4; ++j)
            d[base + i * P + j] = t[i][j];
    __syncthreads();

    // Greedy backtrack, lane 0 only. Halo cells are exactly INFV = the
    // reference's where(valid, dvals, INF); strict '<' scan in OFFS order
    // replicates jnp.argmin first-min tie-breaking.
    if (tid == 0) {
        const int drr[8] = {-1, -1, -1,  0, 0,  1, 1, 1};
        const int dcc[8] = {-1,  0,  1, -1, 1, -1, 0, 1};
        int pr = target[2 * b];
        int pc = target[2 * b + 1];
        float* ob = out + b * (GH * GW);
        for (int step = 0; step < GH * GW; ++step) {
            ob[pr * GW + pc] = 1.0f;
            if (pr == sr && pc == sc) break;
            float best = INFV;
            int bj = 0;
            #pragma unroll
            for (int j = 0; j < 8; ++j) {
                const float vv = d[(pr + drr[j] + 1) * P + (pc + dcc[j] + 1)];
                if (vv < best) { best = vv; bj = j; }
            }
            pr += drr[bj];
            pc += dcc[bj];
        }
    }
}

extern "C" void kernel_launch(void* const* d_in, const int* in_sizes, int n_in,
                              void* d_out, int out_size, void* d_ws, size_t ws_size,
                              hipStream_t stream) {
    const float* weights = (const float*)d_in[0];
    const int*   source  = (const int*)d_in[1];
    const int*   target  = (const int*)d_in[2];
    float*       out     = (float*)d_out;
    const int B = in_sizes[0] / (GH * GW);
    bbastar_kernel<<<B, 64, 0, stream>>>(weights, source, target, out);
}